// Round 4
// baseline (366.988 us; speedup 1.0000x reference)
//
#include <hip/hip_runtime.h>
#include <stdint.h>

typedef short short8 __attribute__((ext_vector_type(8)));
typedef float f32x4 __attribute__((ext_vector_type(4)));

#define B_    4
#define M_    2048
#define D_    1024
#define NH_   16
#define DH_   64
#define LOG2E 1.44269504f

__device__ __forceinline__ short f2bf(float f) {
  union { float f; uint32_t u; } v; v.f = f;
  uint32_t r = (v.u + 0x7fffu + ((v.u >> 16) & 1u)) >> 16;  // RNE
  return (short)r;
}

__device__ __forceinline__ void gl_lds16(const void* g, void* l) {
  __builtin_amdgcn_global_load_lds(
      (__attribute__((address_space(1))) void*)(g),
      (__attribute__((address_space(3))) void*)(l),
      16, 0, 0);
}

__device__ __forceinline__ f32x4 mfma16(short8 a, short8 b, f32x4 c) {
  return __builtin_amdgcn_mfma_f32_16x16x32_bf16(a, b, c, 0, 0, 0);
}

// ---------------- fp32 -> bf16 cast, all 5 tensors in one launch ----------------
__global__ __launch_bounds__(256) void cvt_all(const float* __restrict__ H,
                                               const float* __restrict__ s0,
                                               const float* __restrict__ s1,
                                               const float* __restrict__ s2,
                                               const float* __restrict__ s3,
                                               short* __restrict__ dH,
                                               short* __restrict__ d0,
                                               short* __restrict__ d1,
                                               short* __restrict__ d2,
                                               short* __restrict__ d3) {
  const int bidx = blockIdx.x;
  const float* src;
  short* dst;
  int i;
  if (bidx < 8192) {
    src = H; dst = dH; i = bidx * 256 + threadIdx.x;
  } else {
    const int y = (bidx - 8192) >> 10;
    src = (y == 0) ? s0 : (y == 1) ? s1 : (y == 2) ? s2 : s3;
    dst = (y == 0) ? d0 : (y == 1) ? d1 : (y == 2) ? d2 : d3;
    i = ((bidx - 8192) & 1023) * 256 + threadIdx.x;
  }
  float4 v = ((const float4*)src)[i];
  short4 o;
  o.x = f2bf(v.x); o.y = f2bf(v.y); o.z = f2bf(v.z); o.w = f2bf(v.w);
  ((short4*)dst)[i] = o;
}

// ---------------- fused QKV projection GEMM (R11: no-LDS register GEMM) ----------------
// R8/R10 post-mortem: 3 schedules all ~55us/40% MfmaUtil => resource-bound,
// not schedule-bound. time/tile == LDS(2000cy) + MFMA(1860cy) SERIAL, and
// occupancy is really ~5.6 waves/CU (320 unified regs), so no cross-block
// overlap exists to hide the LDS phase. Fix: remove LDS from the K-loop.
// All fragments load global->register (16 rows x 64B per dwordx4 -- L1/L2
// friendly; per-CU-tile distinct footprint 32KB fits L1; A panel 2MB/XCD is
// L2-resident). Zero barriers + zero LDS ops in the loop: waves drift
// freely, compiler scoreboard emits counted per-use vmcnt, and each phase
// issues the NEXT phase's loads before its MFMA cluster (static 2-tile
// register rotation aE/aO, bX/bY -- all compile-time indices).
__global__ __launch_bounds__(256, 2) void gemm_qkv(const short* __restrict__ A,
                                                   const short* __restrict__ Wqb,
                                                   const short* __restrict__ Wkb,
                                                   const short* __restrict__ Wvb,
                                                   const float* __restrict__ bq,
                                                   const float* __restrict__ bk,
                                                   const float* __restrict__ bv,
                                                   short* __restrict__ Qo,
                                                   short* __restrict__ Ko,
                                                   short* __restrict__ Vo) {
  __shared__ char smem_raw[34816];  // epilogue transpose buffer ONLY

  const int L = blockIdx.x + 8 * blockIdx.y;  // 512 blocks
  const int xcd = L & 7;
  const int s = L >> 3;        // 0..63
  const int m_local = s & 7;
  const int nt = s >> 3;       // 0..7
  const int m0 = (xcd * 8 + m_local) * 128;
  const int n0 = nt * 128;

  const int tid = threadIdx.x;
  const int w = tid >> 6, l = tid & 63;
  const int q4 = l >> 4, c = l & 15;
  const int wr = w >> 1, wc = w & 1;

  f32x4 acc[3][4][4] = {};

  // per-lane fragment base pointers: element [row][k] at row*1024 + k
  // frag (i|j): row += {i,j}*16  (offset {i,j}*16384 shorts); K-step: +32 shorts
  const short* Ap = A   + (size_t)(m0 + wr * 64 + c) * 1024 + q4 * 8;
  const short* Bq_ = Wqb + (size_t)(n0 + wc * 64 + c) * 1024 + q4 * 8;
  const short* Bk_ = Wkb + (size_t)(n0 + wc * 64 + c) * 1024 + q4 * 8;
  const short* Bv_ = Wvb + (size_t)(n0 + wc * 64 + c) * 1024 + q4 * 8;

  short8 aE[4], aO[4], bX[4], bY[4];

#define LD4(dst, base, kofs)                                              \
  _Pragma("unroll") for (int u = 0; u < 4; ++u)                           \
      dst[u] = *(const short8*)((base) + u * 16384 + (kofs));
#define MM(z, a, b)                                                       \
  __builtin_amdgcn_s_setprio(1);                                          \
  _Pragma("unroll") for (int i = 0; i < 4; ++i)                           \
      _Pragma("unroll") for (int j = 0; j < 4; ++j)                       \
          acc[z][i][j] = mfma16(a[i], b[j], acc[z][i][j]);                \
  __builtin_amdgcn_s_setprio(0);

  // prologue: tile 0 A + B0
  LD4(aE, Ap, 0);
  LD4(bX, Bq_, 0);

  for (int t = 0; t < 32; t += 2) {
    const int k0 = t * 32;
    const int k1 = k0 + 32;
    const int k2 = ((t + 2) & 31) * 32;  // wraps to 0 on last iter (loads unused, in-bounds)
    // ---- tile t (even): a=aE, z0 consumes bX ----
    LD4(bY, Bk_, k0);          // issue B1(t) during z0 MFMA
    MM(0, aE, bX);
    LD4(bX, Bv_, k0);          // issue B2(t) during z1 MFMA
    MM(1, aE, bY);
    LD4(aO, Ap, k1);           // issue A(t+1), B0(t+1) during z2 MFMA
    LD4(bY, Bq_, k1);
    MM(2, aE, bX);
    // ---- tile t+1 (odd): a=aO, z0 consumes bY ----
    LD4(bX, Bk_, k1);
    MM(0, aO, bY);
    LD4(bY, Bv_, k1);
    MM(1, aO, bX);
    LD4(aE, Ap, k2);
    LD4(bX, Bq_, k2);
    MM(2, aO, bY);
  }

#undef LD4
#undef MM

  // ---- epilogues: Q then K (row-major), then V (transposed), via Cb LDS ----
#pragma unroll
  for (int z = 0; z < 2; ++z) {
    short* Cb = (short*)smem_raw;
    const float* bias = z ? bk : bq;
    short* outp = z ? Ko : Qo;
    const float scale = z ? 1.0f : 0.125f;
#pragma unroll
    for (int j = 0; j < 4; ++j) {
      const float bvv = bias[n0 + wc * 64 + j * 16 + c];
#pragma unroll
      for (int i = 0; i < 4; ++i)
#pragma unroll
        for (int r = 0; r < 4; ++r)
          Cb[(wr * 64 + i * 16 + q4 * 4 + r) * 136 + wc * 64 + j * 16 + c] =
              f2bf((acc[z][i][j][r] + bvv) * scale);
    }
    __syncthreads();
#pragma unroll
    for (int p = 0; p < 8; ++p) {
      const int g = p * 256 + tid;
      const int row = g >> 4, seg = g & 15;
      *(short8*)(outp + (size_t)(m0 + row) * 1024 + n0 + seg * 8) =
          *(const short8*)(Cb + row * 136 + seg * 8);
    }
    __syncthreads();
  }
  {
    short* Cb = (short*)smem_raw;
#pragma unroll
    for (int j = 0; j < 4; ++j) {
      const float bvv = bv[n0 + wc * 64 + j * 16 + c];
#pragma unroll
      for (int i = 0; i < 4; ++i) {
        short4 pk;
        pk.x = f2bf(acc[2][i][j][0] + bvv);
        pk.y = f2bf(acc[2][i][j][1] + bvv);
        pk.z = f2bf(acc[2][i][j][2] + bvv);
        pk.w = f2bf(acc[2][i][j][3] + bvv);
        *(short4*)(Cb + (wc * 64 + j * 16 + c) * 136 + wr * 64 + i * 16 + q4 * 4) = pk;
      }
    }
    __syncthreads();
    const int bb = m0 >> 11;
    const int tokb = m0 & 2047;
#pragma unroll
    for (int p = 0; p < 8; ++p) {
      const int g = p * 256 + tid;
      const int col = g >> 4, rseg = g & 15;
      const int colg = n0 + col;
      const int hh = colg >> 6, dd = colg & 63;
      *(short8*)(Vo + ((size_t)(bb * NH_ + hh) * DH_ + dd) * M_ + tokb + rseg * 8) =
          *(const short8*)(Cb + col * 136 + rseg * 8);
    }
  }
}

// ---------------- output projection GEMM (ping-pong K-loop, LDS fp32 epi) ----------------
__global__ __launch_bounds__(256) void gemm_oproj(const short* __restrict__ A,
                                                  const short* __restrict__ Bt,
                                                  const float* __restrict__ bias,
                                                  const int* __restrict__ pmask,
                                                  float* __restrict__ outp) {
  __shared__ char smem[24576];
  short* Ab0 = (short*)smem;             // 128x32 (8 KB)
  short* Ab1 = (short*)(smem + 8192);
  short* Bb0 = (short*)(smem + 16384);   // 64x32 (4 KB)
  short* Bb1 = (short*)(smem + 20480);

  const int L = blockIdx.x + 16 * blockIdx.y;  // 1024 blocks
  const int xcd = L & 7;
  const int s = L >> 3;
  const int m_local = s & 7;
  const int nt = s >> 3;
  const int m0 = (xcd * 8 + m_local) * 128;
  const int n0 = nt * 64;

  const int tid = threadIdx.x;
  const int w = tid >> 6, l = tid & 63;
  const int q4 = l >> 4, c = l & 15;
  const int wr = w >> 1, wc = w & 1;

  f32x4 acc[4][2] = {};
  const int arow = (l >> 2);
  const int acol = (l & 3) * 8;

  // prologue: tile 0 -> buf0
#pragma unroll
  for (int st = 0; st < 2; ++st) {
    const int chunk = w * 2 + st;
    gl_lds16(A + (size_t)(m0 + chunk * 16 + arow) * 1024 + acol, Ab0 + chunk * 512);
  }
  gl_lds16(Bt + (size_t)(n0 + w * 16 + arow) * 1024 + acol, Bb0 + w * 512);
  __syncthreads();

  for (int kk = 0; kk < 32; ++kk) {
    const int cur = kk & 1;
    if (kk + 1 < 32) {
      const int k0n = (kk + 1) * 32;
#pragma unroll
      for (int st = 0; st < 2; ++st) {
        const int chunk = w * 2 + st;
        gl_lds16(A + (size_t)(m0 + chunk * 16 + arow) * 1024 + k0n + acol,
                 (cur ? Ab0 : Ab1) + chunk * 512);
      }
      gl_lds16(Bt + (size_t)(n0 + w * 16 + arow) * 1024 + k0n + acol,
               (cur ? Bb0 : Bb1) + w * 512);
    }
    const short* Ab = cur ? Ab1 : Ab0;
    const short* Bb = cur ? Bb1 : Bb0;
    short8 af[4], bfr[2];
#pragma unroll
    for (int i = 0; i < 4; ++i)
      af[i] = *(const short8*)(Ab + (wr * 64 + i * 16 + c) * 32 + q4 * 8);
#pragma unroll
    for (int j = 0; j < 2; ++j)
      bfr[j] = *(const short8*)(Bb + (wc * 32 + j * 16 + c) * 32 + q4 * 8);
#pragma unroll
    for (int i = 0; i < 4; ++i)
#pragma unroll
      for (int j = 0; j < 2; ++j)
        acc[i][j] = mfma16(af[i], bfr[j], acc[i][j]);
    __syncthreads();
  }

  // fp32 epilogue: two 64-row halves through LDS [64][68], float4 stores
  float* Cf = (float*)smem;
#pragma unroll
  for (int half = 0; half < 2; ++half) {
    __syncthreads();
    if (wr == half) {
#pragma unroll
      for (int j = 0; j < 2; ++j) {
        const float bvv = bias[n0 + wc * 32 + j * 16 + c];
#pragma unroll
        for (int i = 0; i < 4; ++i)
#pragma unroll
          for (int r = 0; r < 4; ++r)
            Cf[(i * 16 + q4 * 4 + r) * 68 + wc * 32 + j * 16 + c] =
                acc[i][j][r] + bvv;
      }
    }
    __syncthreads();
#pragma unroll
    for (int p = 0; p < 4; ++p) {
      const int g = p * 256 + tid;
      const int row = g >> 4, seg = g & 15;
      const int rowg = m0 + half * 64 + row;
      const float mmv = (pmask[rowg] > 0) ? 1.0f : 0.0f;
      float4 v = *(const float4*)(Cf + row * 68 + seg * 4);
      v.x *= mmv; v.y *= mmv; v.z *= mmv; v.w *= mmv;
      *(float4*)(outp + (size_t)rowg * 1024 + n0 + seg * 4) = v;
    }
  }
}

// ---------------- windowed attention (unchanged) ----------------
__global__ __launch_bounds__(256) void attn_kernel(const short* __restrict__ Qb,
                                                   const short* __restrict__ Kb,
                                                   const short* __restrict__ Vtb,
                                                   const int* __restrict__ pmask,
                                                   short* __restrict__ Attb) {
  __shared__ char smem[20480];
  short* Ks0 = (short*)smem;             // 32x64 (4 KB)
  short* Ks1 = (short*)(smem + 4096);
  short* Vs0 = (short*)(smem + 8192);    // 64x32 (4 KB)
  short* Vs1 = (short*)(smem + 12288);
  short* Ps  = (short*)(smem + 16384);   // 4 waves x 16x32 (4 KB)

  const int tid = threadIdx.x;
  const int w = tid >> 6, l = tid & 63;
  const int q4 = l >> 4, c = l & 15;
  const int qt = blockIdx.x, h = blockIdx.y, b = blockIdx.z;
  const short* Qrow = Qb + (size_t)(b * M_) * D_ + h * DH_;
  const short* Kbase = Kb + (size_t)(b * M_) * D_ + h * DH_;
  const short* Vbase = Vtb + (size_t)(b * NH_ + h) * DH_ * M_;
  const int qrow0 = qt * 64 + w * 16;

  short8 aq0 = *(const short8*)(Qrow + (size_t)(qrow0 + c) * D_ + q4 * 8);
  short8 aq1 = *(const short8*)(Qrow + (size_t)(qrow0 + c) * D_ + 32 + q4 * 8);

  const int jt0 = max(0, 2 * qt - 2);
  const int jt1 = min(M_ / 32 - 1, 2 * qt + 3);

  const int kh = tid >> 7, krow = (tid >> 2) & 31, ch = tid & 3;
  const int vrow = tid >> 2;

  {
    const int j0 = jt0 * 32;
    gl_lds16(Kbase + (size_t)(j0 + krow) * D_ + kh * 32 + ch * 8, (char*)Ks0 + tid * 16);
    gl_lds16(Vbase + (size_t)vrow * M_ + j0 + ch * 8, (char*)Vs0 + tid * 16);
  }
  __syncthreads();

  f32x4 o[4] = {};
  float lrun[4] = {0.f, 0.f, 0.f, 0.f};
  short* Pw = Ps + w * 512;

  for (int jt = jt0; jt <= jt1; ++jt) {
    const int buf = (jt - jt0) & 1;
    const int j0 = jt * 32;
    if (jt < jt1) {
      const int j0n = j0 + 32;
      gl_lds16(Kbase + (size_t)(j0n + krow) * D_ + kh * 32 + ch * 8,
               (char*)(buf ? Ks0 : Ks1) + tid * 16);
      gl_lds16(Vbase + (size_t)vrow * M_ + j0n + ch * 8,
               (char*)(buf ? Vs0 : Vs1) + tid * 16);
    }
    const short* Kt = buf ? Ks1 : Ks0;
    const short* Vt = buf ? Vs1 : Vs0;
    short8 b00 = *(const short8*)(Kt + c * 32 + q4 * 8);
    short8 b10 = *(const short8*)(Kt + 1024 + c * 32 + q4 * 8);
    short8 b01 = *(const short8*)(Kt + (16 + c) * 32 + q4 * 8);
    short8 b11 = *(const short8*)(Kt + 1024 + (16 + c) * 32 + q4 * 8);
    f32x4 s0 = {}, s1 = {};
    s0 = mfma16(aq0, b00, s0);
    s0 = mfma16(aq1, b10, s0);
    s1 = mfma16(aq0, b01, s1);
    s1 = mfma16(aq1, b11, s1);

    const float w0m = (pmask[b * M_ + j0 + c] > 0) ? 1.f : 0.f;
    const float w1m = (pmask[b * M_ + j0 + 16 + c] > 0) ? 1.f : 0.f;

#pragma unroll
    for (int r = 0; r < 4; ++r) {
      const int qr = qrow0 + q4 * 4 + r;
      const float d0 = fminf(fabsf((float)(qr - (j0 + c))), 28.0f);
      const float d1 = fminf(fabsf((float)(qr - (j0 + 16 + c))), 28.0f);
      const float p0 = exp2f((s0[r] - d0) * LOG2E) * w0m;
      const float p1 = exp2f((s1[r] - d1) * LOG2E) * w1m;
      Pw[(q4 * 4 + r) * 32 + c] = f2bf(p0);
      Pw[(q4 * 4 + r) * 32 + 16 + c] = f2bf(p1);
      lrun[r] += p0 + p1;
    }
    short8 pa = *(const short8*)(Pw + c * 32 + q4 * 8);
#pragma unroll
    for (int f = 0; f < 4; ++f) {
      short8 bv = *(const short8*)(Vt + (f * 16 + c) * 32 + q4 * 8);
      o[f] = mfma16(pa, bv, o[f]);
    }
    __syncthreads();
  }

#pragma unroll
  for (int r = 0; r < 4; ++r) {
#pragma unroll
    for (int off = 1; off < 16; off <<= 1)
      lrun[r] += __shfl_xor(lrun[r], off);
  }

  short* Cb = (short*)smem;
#pragma unroll
  for (int r = 0; r < 4; ++r) {
    const float inv = 1.0f / lrun[r];
#pragma unroll
    for (int f = 0; f < 4; ++f)
      Cb[(w * 16 + q4 * 4 + r) * 72 + f * 16 + c] = f2bf(o[f][r] * inv);
  }
  __syncthreads();
#pragma unroll
  for (int p = 0; p < 2; ++p) {
    const int u = p * 256 + tid;
    const int row = u >> 3, seg = u & 7;
    *(short8*)(Attb + (size_t)(b * M_ + qt * 64 + row) * D_ + h * DH_ + seg * 8) =
        *(const short8*)(Cb + row * 72 + seg * 8);
  }
}

extern "C" void kernel_launch(void* const* d_in, const int* in_sizes, int n_in,
                              void* d_out, int out_size, void* d_ws, size_t ws_size,
                              hipStream_t stream) {
  const float* H     = (const float*)d_in[0];
  const int*   pmask = (const int*)d_in[1];
  const float* Wq    = (const float*)d_in[2];
  const float* bq    = (const float*)d_in[3];
  const float* Wk    = (const float*)d_in[4];
  const float* bk    = (const float*)d_in[5];
  const float* Wv    = (const float*)d_in[6];
  const float* bv    = (const float*)d_in[7];
  const float* Wo    = (const float*)d_in[8];
  const float* bo    = (const float*)d_in[9];
  float* out = (float*)d_out;
  char* ws = (char*)d_ws;

  short* Hb   = (short*)(ws);                  // 16 MB  (B*M x D bf16)
  short* Attb = (short*)(ws);                  // alias of Hb (dead after qkv)
  short* Wqb  = (short*)(ws + (16u << 20));
  short* Wkb  = (short*)(ws + (18u << 20));
  short* Wvb  = (short*)(ws + (20u << 20));
  short* Wob  = (short*)(ws + (22u << 20));
  short* Qb   = (short*)(ws + (24u << 20));    // 16 MB (B*M,1024), pre-scaled 1/8
  short* Kb2  = (short*)(ws + (40u << 20));    // 16 MB (B*M,1024)
  short* Vtb  = (short*)(ws + (56u << 20));    // 16 MB (B,NH,DH,M)

  cvt_all<<<8192 + 4096, 256, 0, stream>>>(H, Wq, Wk, Wv, Wo,
                                           Hb, Wqb, Wkb, Wvb, Wob);

  gemm_qkv<<<dim3(8, 64), 256, 0, stream>>>(Hb, Wqb, Wkb, Wvb, bq, bk, bv,
                                            Qb, Kb2, Vtb);

  attn_kernel<<<dim3(M_ / 64, NH_, B_), 256, 0, stream>>>(Qb, Kb2, Vtb, pmask, Attb);

  gemm_oproj<<<dim3(16, 64), 256, 0, stream>>>(Attb, Wob, bo, pmask, out);
}

// Round 5
// 217.137 us; speedup vs baseline: 1.6901x; 1.6901x over previous
//
#include <hip/hip_runtime.h>
#include <stdint.h>

typedef short short8 __attribute__((ext_vector_type(8)));
typedef float f32x4 __attribute__((ext_vector_type(4)));

#define B_    4
#define M_    2048
#define D_    1024
#define NH_   16
#define DH_   64
#define LOG2E 1.44269504f

__device__ __forceinline__ short f2bf(float f) {
  union { float f; uint32_t u; } v; v.f = f;
  uint32_t r = (v.u + 0x7fffu + ((v.u >> 16) & 1u)) >> 16;  // RNE
  return (short)r;
}

__device__ __forceinline__ void gl_lds16(const void* g, void* l) {
  __builtin_amdgcn_global_load_lds(
      (__attribute__((address_space(1))) void*)(g),
      (__attribute__((address_space(3))) void*)(l),
      16, 0, 0);
}

__device__ __forceinline__ f32x4 mfma16(short8 a, short8 b, f32x4 c) {
  return __builtin_amdgcn_mfma_f32_16x16x32_bf16(a, b, c, 0, 0, 0);
}

// counted waits (separate from barriers; barriers stay compiler-visible)
#define VM_WAIT(N)  asm volatile("s_waitcnt vmcnt(" #N ")" ::: "memory")
#define LGKM_WAIT() asm volatile("s_waitcnt lgkmcnt(0)" ::: "memory")
#define BAR_FENCE()                    \
  __builtin_amdgcn_s_barrier();        \
  __builtin_amdgcn_sched_barrier(0)

// ---------------- fp32 -> bf16 cast, all 5 tensors in one launch ----------------
__global__ __launch_bounds__(256) void cvt_all(const float* __restrict__ H,
                                               const float* __restrict__ s0,
                                               const float* __restrict__ s1,
                                               const float* __restrict__ s2,
                                               const float* __restrict__ s3,
                                               short* __restrict__ dH,
                                               short* __restrict__ d0,
                                               short* __restrict__ d1,
                                               short* __restrict__ d2,
                                               short* __restrict__ d3) {
  const int bidx = blockIdx.x;
  const float* src;
  short* dst;
  int i;
  if (bidx < 8192) {
    src = H; dst = dH; i = bidx * 256 + threadIdx.x;
  } else {
    const int y = (bidx - 8192) >> 10;
    src = (y == 0) ? s0 : (y == 1) ? s1 : (y == 2) ? s2 : s3;
    dst = (y == 0) ? d0 : (y == 1) ? d1 : (y == 2) ? d2 : d3;
    i = ((bidx - 8192) & 1023) * 256 + threadIdx.x;
  }
  float4 v = ((const float4*)src)[i];
  short4 o;
  o.x = f2bf(v.x); o.y = f2bf(v.y); o.z = f2bf(v.z); o.w = f2bf(v.w);
  ((short4*)dst)[i] = o;
}

// ---------------- fused QKV projection GEMM ----------------
// R12: R10's proven 3-phase counted-vmcnt schedule, RESIZED for occupancy.
// Post-mortem chain: R8/R10 (acc=192, ~320 unified regs) = 1 block/CU =
// one lockstep barrier group = LDS phase and MFMA phase serialize chip-wide;
// R11 (no-LDS) spilled (WRITE_SIZE 542MB = scratch). Fix: 128x64 tile,
// acc[3][4][2]=96 regs (~150/wave total) -> 2-3 blocks/CU, independent
// barrier groups overlap anti-phase (m114 mechanism). LDS 20KB single-buf.
// FIFO per wave: A,A,B0 | B1 | B2 (5 in flight); waits 2/4/4, peel 2/1/0.
__global__ __launch_bounds__(256, 2) void gemm_qkv(const short* __restrict__ A,
                                                   const short* __restrict__ Wqb,
                                                   const short* __restrict__ Wkb,
                                                   const short* __restrict__ Wvb,
                                                   const float* __restrict__ bq,
                                                   const float* __restrict__ bk,
                                                   const float* __restrict__ bv,
                                                   short* __restrict__ Qo,
                                                   short* __restrict__ Ko,
                                                   short* __restrict__ Vo) {
  __shared__ char smem_raw[20480];           // staging 20K; epilogue <= 18.5K
  short* As  = (short*)smem_raw;             // 128x32 (8 KB)
  short* Bs0 = (short*)(smem_raw + 8192);    // 64x32 (4 KB)
  short* Bs1 = (short*)(smem_raw + 12288);
  short* Bs2 = (short*)(smem_raw + 16384);

  const int L = blockIdx.x + 8 * blockIdx.y;  // 1024 blocks
  const int xcd = L & 7;
  const int s = L >> 3;        // 0..127
  const int m_local = s & 7;
  const int nt = s >> 3;       // 0..15
  const int m0 = (xcd * 8 + m_local) * 128;
  const int n0 = nt * 64;

  const int tid = threadIdx.x;
  const int w = tid >> 6, l = tid & 63;
  const int q4 = l >> 4, c = l & 15;
  const int wr = w >> 1, wc = w & 1;

  f32x4 acc[3][4][2] = {};
  const int arow = (l >> 2);
  // inverse-swizzled global source column (16B chunk permutation within 64B row)
  const int acol = ((l & 3) ^ ((l >> 3) & 3)) * 8;
  // swizzled LDS read offset (lane-constant across all fragment reads)
  const int q4s = (q4 ^ ((c >> 1) & 3)) * 8;

  const short* Bz0 = Wqb;
  const short* Bz1 = Wkb;
  const short* Bz2 = Wvb;

  // per-wave staging geometry: A = 2 chunks/wave, each B = 1 chunk/wave
  const int ch0 = w * 2, ch1 = w * 2 + 1;
  const size_t roA0 = (size_t)(ch0 * 16 + arow) * 1024 + acol;
  const size_t roA1 = (size_t)(ch1 * 16 + arow) * 1024 + acol;
  const size_t roB  = (size_t)(w * 16 + arow) * 1024 + acol;
  const size_t Abase = (size_t)m0 * 1024;
  const size_t Bbase = (size_t)n0 * 1024;
  short* dA0 = As + ch0 * 512;
  short* dA1 = As + ch1 * 512;
  short* dB0 = Bs0 + w * 512;
  short* dB1 = Bs1 + w * 512;
  short* dB2 = Bs2 + w * 512;

  // prologue: tile 0, FIFO order matches steady state: A,A,B0 | B1 | B2
  gl_lds16(A + Abase + roA0, dA0);
  gl_lds16(A + Abase + roA1, dA1);
  gl_lds16(Bz0 + Bbase + roB, dB0);
  gl_lds16(Bz1 + Bbase + roB, dB1);
  gl_lds16(Bz2 + Bbase + roB, dB2);

  short8 af[4], bfr[2];

#define READ_A()                                                        \
  _Pragma("unroll") for (int i = 0; i < 4; ++i)                         \
      af[i] = *(const short8*)(As + (wr * 64 + i * 16 + c) * 32 + q4s);
#define READ_B(Bs)                                                      \
  _Pragma("unroll") for (int j = 0; j < 2; ++j)                         \
      bfr[j] = *(const short8*)((Bs) + (wc * 32 + j * 16 + c) * 32 + q4s);
#define MFMA_Z(z)                                                       \
  __builtin_amdgcn_s_setprio(1);                                        \
  _Pragma("unroll") for (int i = 0; i < 4; ++i)                         \
      _Pragma("unroll") for (int j = 0; j < 2; ++j)                     \
          acc[z][i][j] = mfma16(af[i], bfr[j], acc[z][i][j]);           \
  __builtin_amdgcn_s_setprio(0);

  for (int kk = 0; kk < 31; ++kk) {
    const size_t ko = (size_t)(kk + 1) * 32;
    // ---- phase 0: z=0 (A + B0) ----
    VM_WAIT(2);
    BAR_FENCE();
    READ_A();
    READ_B(Bs0);
    MFMA_Z(0);
    LGKM_WAIT();
    BAR_FENCE();
    gl_lds16(A + Abase + ko + roA0, dA0);
    gl_lds16(A + Abase + ko + roA1, dA1);
    gl_lds16(Bz0 + Bbase + ko + roB, dB0);
    // ---- phase 1: z=1 (B1) ----
    VM_WAIT(4);
    BAR_FENCE();
    READ_B(Bs1);
    MFMA_Z(1);
    LGKM_WAIT();
    BAR_FENCE();
    gl_lds16(Bz1 + Bbase + ko + roB, dB1);
    // ---- phase 2: z=2 (B2) ----
    VM_WAIT(4);
    BAR_FENCE();
    READ_B(Bs2);
    MFMA_Z(2);
    LGKM_WAIT();
    BAR_FENCE();
    gl_lds16(Bz2 + Bbase + ko + roB, dB2);
  }
  // ---- peeled last tile (kk = 31): no further issues; drain 2/1/0 ----
  VM_WAIT(2);
  BAR_FENCE();
  READ_A();
  READ_B(Bs0);
  MFMA_Z(0);
  VM_WAIT(1);
  BAR_FENCE();
  READ_B(Bs1);
  MFMA_Z(1);
  VM_WAIT(0);
  BAR_FENCE();
  READ_B(Bs2);
  MFMA_Z(2);

#undef READ_A
#undef READ_B
#undef MFMA_Z

  __syncthreads();  // all reads drained; smem now reusable for epilogue

  // ---- epilogues: Q then K (row-major, Cb[128][72]), then V (transposed) ----
#pragma unroll
  for (int z = 0; z < 2; ++z) {
    short* Cb = (short*)smem_raw;
    const float* bias = z ? bk : bq;
    short* outp = z ? Ko : Qo;
    const float scale = z ? 1.0f : 0.125f;
#pragma unroll
    for (int j = 0; j < 2; ++j) {
      const float bvv = bias[n0 + wc * 32 + j * 16 + c];
#pragma unroll
      for (int i = 0; i < 4; ++i)
#pragma unroll
        for (int r = 0; r < 4; ++r)
          Cb[(wr * 64 + i * 16 + q4 * 4 + r) * 72 + wc * 32 + j * 16 + c] =
              f2bf((acc[z][i][j][r] + bvv) * scale);
    }
    __syncthreads();
#pragma unroll
    for (int p = 0; p < 4; ++p) {
      const int g = p * 256 + tid;
      const int row = g >> 3, seg = g & 7;
      *(short8*)(outp + (size_t)(m0 + row) * 1024 + n0 + seg * 8) =
          *(const short8*)(Cb + row * 72 + seg * 8);
    }
    __syncthreads();
  }
  {
    short* Cb = (short*)smem_raw;  // [64][136] col-major staging for V^T
#pragma unroll
    for (int j = 0; j < 2; ++j) {
      const float bvv = bv[n0 + wc * 32 + j * 16 + c];
#pragma unroll
      for (int i = 0; i < 4; ++i) {
        short4 pk;
        pk.x = f2bf(acc[2][i][j][0] + bvv);
        pk.y = f2bf(acc[2][i][j][1] + bvv);
        pk.z = f2bf(acc[2][i][j][2] + bvv);
        pk.w = f2bf(acc[2][i][j][3] + bvv);
        *(short4*)(Cb + (wc * 32 + j * 16 + c) * 136 + wr * 64 + i * 16 + q4 * 4) = pk;
      }
    }
    __syncthreads();
    const int bb = m0 >> 11;
    const int tokb = m0 & 2047;
#pragma unroll
    for (int p = 0; p < 4; ++p) {
      const int g = p * 256 + tid;
      const int col = g >> 4, rseg = g & 15;
      const int colg = n0 + col;
      const int hh = colg >> 6, dd = colg & 63;
      *(short8*)(Vo + ((size_t)(bb * NH_ + hh) * DH_ + dd) * M_ + tokb + rseg * 8) =
          *(const short8*)(Cb + col * 136 + rseg * 8);
    }
  }
}

// ---------------- output projection GEMM (ping-pong K-loop, LDS fp32 epi) ----------------
__global__ __launch_bounds__(256) void gemm_oproj(const short* __restrict__ A,
                                                  const short* __restrict__ Bt,
                                                  const float* __restrict__ bias,
                                                  const int* __restrict__ pmask,
                                                  float* __restrict__ outp) {
  __shared__ char smem[24576];
  short* Ab0 = (short*)smem;             // 128x32 (8 KB)
  short* Ab1 = (short*)(smem + 8192);
  short* Bb0 = (short*)(smem + 16384);   // 64x32 (4 KB)
  short* Bb1 = (short*)(smem + 20480);

  const int L = blockIdx.x + 16 * blockIdx.y;  // 1024 blocks
  const int xcd = L & 7;
  const int s = L >> 3;
  const int m_local = s & 7;
  const int nt = s >> 3;
  const int m0 = (xcd * 8 + m_local) * 128;
  const int n0 = nt * 64;

  const int tid = threadIdx.x;
  const int w = tid >> 6, l = tid & 63;
  const int q4 = l >> 4, c = l & 15;
  const int wr = w >> 1, wc = w & 1;

  f32x4 acc[4][2] = {};
  const int arow = (l >> 2);
  const int acol = (l & 3) * 8;

  // prologue: tile 0 -> buf0
#pragma unroll
  for (int st = 0; st < 2; ++st) {
    const int chunk = w * 2 + st;
    gl_lds16(A + (size_t)(m0 + chunk * 16 + arow) * 1024 + acol, Ab0 + chunk * 512);
  }
  gl_lds16(Bt + (size_t)(n0 + w * 16 + arow) * 1024 + acol, Bb0 + w * 512);
  __syncthreads();

  for (int kk = 0; kk < 32; ++kk) {
    const int cur = kk & 1;
    if (kk + 1 < 32) {
      const int k0n = (kk + 1) * 32;
#pragma unroll
      for (int st = 0; st < 2; ++st) {
        const int chunk = w * 2 + st;
        gl_lds16(A + (size_t)(m0 + chunk * 16 + arow) * 1024 + k0n + acol,
                 (cur ? Ab0 : Ab1) + chunk * 512);
      }
      gl_lds16(Bt + (size_t)(n0 + w * 16 + arow) * 1024 + k0n + acol,
               (cur ? Bb0 : Bb1) + w * 512);
    }
    const short* Ab = cur ? Ab1 : Ab0;
    const short* Bb = cur ? Bb1 : Bb0;
    short8 af[4], bfr[2];
#pragma unroll
    for (int i = 0; i < 4; ++i)
      af[i] = *(const short8*)(Ab + (wr * 64 + i * 16 + c) * 32 + q4 * 8);
#pragma unroll
    for (int j = 0; j < 2; ++j)
      bfr[j] = *(const short8*)(Bb + (wc * 32 + j * 16 + c) * 32 + q4 * 8);
#pragma unroll
    for (int i = 0; i < 4; ++i)
#pragma unroll
      for (int j = 0; j < 2; ++j)
        acc[i][j] = mfma16(af[i], bfr[j], acc[i][j]);
    __syncthreads();
  }

  // fp32 epilogue: two 64-row halves through LDS [64][68], float4 stores
  float* Cf = (float*)smem;
#pragma unroll
  for (int half = 0; half < 2; ++half) {
    __syncthreads();
    if (wr == half) {
#pragma unroll
      for (int j = 0; j < 2; ++j) {
        const float bvv = bias[n0 + wc * 32 + j * 16 + c];
#pragma unroll
        for (int i = 0; i < 4; ++i)
#pragma unroll
          for (int r = 0; r < 4; ++r)
            Cf[(i * 16 + q4 * 4 + r) * 68 + wc * 32 + j * 16 + c] =
                acc[i][j][r] + bvv;
      }
    }
    __syncthreads();
#pragma unroll
    for (int p = 0; p < 4; ++p) {
      const int g = p * 256 + tid;
      const int row = g >> 4, seg = g & 15;
      const int rowg = m0 + half * 64 + row;
      const float mmv = (pmask[rowg] > 0) ? 1.0f : 0.0f;
      float4 v = *(const float4*)(Cf + row * 68 + seg * 4);
      v.x *= mmv; v.y *= mmv; v.z *= mmv; v.w *= mmv;
      *(float4*)(outp + (size_t)rowg * 1024 + n0 + seg * 4) = v;
    }
  }
}

// ---------------- windowed attention (unchanged) ----------------
__global__ __launch_bounds__(256) void attn_kernel(const short* __restrict__ Qb,
                                                   const short* __restrict__ Kb,
                                                   const short* __restrict__ Vtb,
                                                   const int* __restrict__ pmask,
                                                   short* __restrict__ Attb) {
  __shared__ char smem[20480];
  short* Ks0 = (short*)smem;             // 32x64 (4 KB)
  short* Ks1 = (short*)(smem + 4096);
  short* Vs0 = (short*)(smem + 8192);    // 64x32 (4 KB)
  short* Vs1 = (short*)(smem + 12288);
  short* Ps  = (short*)(smem + 16384);   // 4 waves x 16x32 (4 KB)

  const int tid = threadIdx.x;
  const int w = tid >> 6, l = tid & 63;
  const int q4 = l >> 4, c = l & 15;
  const int qt = blockIdx.x, h = blockIdx.y, b = blockIdx.z;
  const short* Qrow = Qb + (size_t)(b * M_) * D_ + h * DH_;
  const short* Kbase = Kb + (size_t)(b * M_) * D_ + h * DH_;
  const short* Vbase = Vtb + (size_t)(b * NH_ + h) * DH_ * M_;
  const int qrow0 = qt * 64 + w * 16;

  short8 aq0 = *(const short8*)(Qrow + (size_t)(qrow0 + c) * D_ + q4 * 8);
  short8 aq1 = *(const short8*)(Qrow + (size_t)(qrow0 + c) * D_ + 32 + q4 * 8);

  const int jt0 = max(0, 2 * qt - 2);
  const int jt1 = min(M_ / 32 - 1, 2 * qt + 3);

  const int kh = tid >> 7, krow = (tid >> 2) & 31, ch = tid & 3;
  const int vrow = tid >> 2;

  {
    const int j0 = jt0 * 32;
    gl_lds16(Kbase + (size_t)(j0 + krow) * D_ + kh * 32 + ch * 8, (char*)Ks0 + tid * 16);
    gl_lds16(Vbase + (size_t)vrow * M_ + j0 + ch * 8, (char*)Vs0 + tid * 16);
  }
  __syncthreads();

  f32x4 o[4] = {};
  float lrun[4] = {0.f, 0.f, 0.f, 0.f};
  short* Pw = Ps + w * 512;

  for (int jt = jt0; jt <= jt1; ++jt) {
    const int buf = (jt - jt0) & 1;
    const int j0 = jt * 32;
    if (jt < jt1) {
      const int j0n = j0 + 32;
      gl_lds16(Kbase + (size_t)(j0n + krow) * D_ + kh * 32 + ch * 8,
               (char*)(buf ? Ks0 : Ks1) + tid * 16);
      gl_lds16(Vbase + (size_t)vrow * M_ + j0n + ch * 8,
               (char*)(buf ? Vs0 : Vs1) + tid * 16);
    }
    const short* Kt = buf ? Ks1 : Ks0;
    const short* Vt = buf ? Vs1 : Vs0;
    short8 b00 = *(const short8*)(Kt + c * 32 + q4 * 8);
    short8 b10 = *(const short8*)(Kt + 1024 + c * 32 + q4 * 8);
    short8 b01 = *(const short8*)(Kt + (16 + c) * 32 + q4 * 8);
    short8 b11 = *(const short8*)(Kt + 1024 + (16 + c) * 32 + q4 * 8);
    f32x4 s0 = {}, s1 = {};
    s0 = mfma16(aq0, b00, s0);
    s0 = mfma16(aq1, b10, s0);
    s1 = mfma16(aq0, b01, s1);
    s1 = mfma16(aq1, b11, s1);

    const float w0m = (pmask[b * M_ + j0 + c] > 0) ? 1.f : 0.f;
    const float w1m = (pmask[b * M_ + j0 + 16 + c] > 0) ? 1.f : 0.f;

#pragma unroll
    for (int r = 0; r < 4; ++r) {
      const int qr = qrow0 + q4 * 4 + r;
      const float d0 = fminf(fabsf((float)(qr - (j0 + c))), 28.0f);
      const float d1 = fminf(fabsf((float)(qr - (j0 + 16 + c))), 28.0f);
      const float p0 = exp2f((s0[r] - d0) * LOG2E) * w0m;
      const float p1 = exp2f((s1[r] - d1) * LOG2E) * w1m;
      Pw[(q4 * 4 + r) * 32 + c] = f2bf(p0);
      Pw[(q4 * 4 + r) * 32 + 16 + c] = f2bf(p1);
      lrun[r] += p0 + p1;
    }
    short8 pa = *(const short8*)(Pw + c * 32 + q4 * 8);
#pragma unroll
    for (int f = 0; f < 4; ++f) {
      short8 bv = *(const short8*)(Vt + (f * 16 + c) * 32 + q4 * 8);
      o[f] = mfma16(pa, bv, o[f]);
    }
    __syncthreads();
  }

#pragma unroll
  for (int r = 0; r < 4; ++r) {
#pragma unroll
    for (int off = 1; off < 16; off <<= 1)
      lrun[r] += __shfl_xor(lrun[r], off);
  }

  short* Cb = (short*)smem;
#pragma unroll
  for (int r = 0; r < 4; ++r) {
    const float inv = 1.0f / lrun[r];
#pragma unroll
    for (int f = 0; f < 4; ++f)
      Cb[(w * 16 + q4 * 4 + r) * 72 + f * 16 + c] = f2bf(o[f][r] * inv);
  }
  __syncthreads();
#pragma unroll
  for (int p = 0; p < 2; ++p) {
    const int u = p * 256 + tid;
    const int row = u >> 3, seg = u & 7;
    *(short8*)(Attb + (size_t)(b * M_ + qt * 64 + row) * D_ + h * DH_ + seg * 8) =
        *(const short8*)(Cb + row * 72 + seg * 8);
  }
}

extern "C" void kernel_launch(void* const* d_in, const int* in_sizes, int n_in,
                              void* d_out, int out_size, void* d_ws, size_t ws_size,
                              hipStream_t stream) {
  const float* H     = (const float*)d_in[0];
  const int*   pmask = (const int*)d_in[1];
  const float* Wq    = (const float*)d_in[2];
  const float* bq    = (const float*)d_in[3];
  const float* Wk    = (const float*)d_in[4];
  const float* bk    = (const float*)d_in[5];
  const float* Wv    = (const float*)d_in[6];
  const float* bv    = (const float*)d_in[7];
  const float* Wo    = (const float*)d_in[8];
  const float* bo    = (const float*)d_in[9];
  float* out = (float*)d_out;
  char* ws = (char*)d_ws;

  short* Hb   = (short*)(ws);                  // 16 MB  (B*M x D bf16)
  short* Attb = (short*)(ws);                  // alias of Hb (dead after qkv)
  short* Wqb  = (short*)(ws + (16u << 20));
  short* Wkb  = (short*)(ws + (18u << 20));
  short* Wvb  = (short*)(ws + (20u << 20));
  short* Wob  = (short*)(ws + (22u << 20));
  short* Qb   = (short*)(ws + (24u << 20));    // 16 MB (B*M,1024), pre-scaled 1/8
  short* Kb2  = (short*)(ws + (40u << 20));    // 16 MB (B*M,1024)
  short* Vtb  = (short*)(ws + (56u << 20));    // 16 MB (B,NH,DH,M)

  cvt_all<<<8192 + 4096, 256, 0, stream>>>(H, Wq, Wk, Wv, Wo,
                                           Hb, Wqb, Wkb, Wvb, Wob);

  gemm_qkv<<<dim3(8, 128), 256, 0, stream>>>(Hb, Wqb, Wkb, Wvb, bq, bk, bv,
                                             Qb, Kb2, Vtb);

  attn_kernel<<<dim3(M_ / 64, NH_, B_), 256, 0, stream>>>(Qb, Kb2, Vtb, pmask, Attb);

  gemm_oproj<<<dim3(16, 64), 256, 0, stream>>>(Attb, Wob, bo, pmask, out);
}

// Round 6
// 209.587 us; speedup vs baseline: 1.7510x; 1.0360x over previous
//
#include <hip/hip_runtime.h>
#include <stdint.h>

typedef short short8 __attribute__((ext_vector_type(8)));
typedef float f32x4 __attribute__((ext_vector_type(4)));

#define B_    4
#define M_    2048
#define D_    1024
#define NH_   16
#define DH_   64
#define LOG2E 1.44269504f

__device__ __forceinline__ short f2bf(float f) {
  union { float f; uint32_t u; } v; v.f = f;
  uint32_t r = (v.u + 0x7fffu + ((v.u >> 16) & 1u)) >> 16;  // RNE
  return (short)r;
}

__device__ __forceinline__ void gl_lds16(const void* g, void* l) {
  __builtin_amdgcn_global_load_lds(
      (__attribute__((address_space(1))) void*)(g),
      (__attribute__((address_space(3))) void*)(l),
      16, 0, 0);
}

__device__ __forceinline__ f32x4 mfma16(short8 a, short8 b, f32x4 c) {
  return __builtin_amdgcn_mfma_f32_16x16x32_bf16(a, b, c, 0, 0, 0);
}

// ---------------- fp32 -> bf16 cast, all 5 tensors in one launch ----------------
__global__ __launch_bounds__(256) void cvt_all(const float* __restrict__ H,
                                               const float* __restrict__ s0,
                                               const float* __restrict__ s1,
                                               const float* __restrict__ s2,
                                               const float* __restrict__ s3,
                                               short* __restrict__ dH,
                                               short* __restrict__ d0,
                                               short* __restrict__ d1,
                                               short* __restrict__ d2,
                                               short* __restrict__ d3) {
  const int bidx = blockIdx.x;
  const float* src;
  short* dst;
  int i;
  if (bidx < 8192) {
    src = H; dst = dH; i = bidx * 256 + threadIdx.x;
  } else {
    const int y = (bidx - 8192) >> 10;
    src = (y == 0) ? s0 : (y == 1) ? s1 : (y == 2) ? s2 : s3;
    dst = (y == 0) ? d0 : (y == 1) ? d1 : (y == 2) ? d2 : d3;
    i = ((bidx - 8192) & 1023) * 256 + threadIdx.x;
  }
  float4 v = ((const float4*)src)[i];
  short4 o;
  o.x = f2bf(v.x); o.y = f2bf(v.y); o.z = f2bf(v.z); o.w = f2bf(v.w);
  ((short4*)dst)[i] = o;
}

// ---------------- fused QKV projection GEMM (R8 revert -- measured best) ----------------
// R13: revert to R8 exactly. Ladder evidence: R8 (2-phase dbuf, z-fused,
// 128x128, swizzle) = 54.3-55.4us; R10 (3-phase counted) = 55-57us; R12
// (128x64, higher occupancy) = 61us. 55us = 937 TF effective = the known
// m97-structure plain-HIP ceiling (MfmaUtil ~37-40%). Keep the measured best.
__global__ __launch_bounds__(256, 2) void gemm_qkv(const short* __restrict__ A,
                                                   const short* __restrict__ Wqb,
                                                   const short* __restrict__ Wkb,
                                                   const short* __restrict__ Wvb,
                                                   const float* __restrict__ bq,
                                                   const float* __restrict__ bk,
                                                   const float* __restrict__ bv,
                                                   short* __restrict__ Qo,
                                                   short* __restrict__ Ko,
                                                   short* __restrict__ Vo) {
  __shared__ char smem_raw[65536];
  short* Ab0 = (short*)smem_raw;            // 128x32 (8 KB)
  short* Ab1 = (short*)(smem_raw + 8192);
  // B buffers: z in {0,1,2}, buf in {0,1}: smem + 16384 + z*16384 + buf*8192

  const int L = blockIdx.x + 8 * blockIdx.y;  // 512 blocks
  const int xcd = L & 7;
  const int s = L >> 3;        // 0..63
  const int m_local = s & 7;
  const int nt = s >> 3;       // 0..7
  const int m0 = (xcd * 8 + m_local) * 128;
  const int n0 = nt * 128;

  const int tid = threadIdx.x;
  const int w = tid >> 6, l = tid & 63;
  const int q4 = l >> 4, c = l & 15;
  const int wr = w >> 1, wc = w & 1;

  f32x4 acc[3][4][4] = {};
  const int arow = (l >> 2);
  // inverse-swizzled global source column (16B chunk permutation within 64B row)
  const int acol = ((l & 3) ^ ((l >> 3) & 3)) * 8;
  // swizzled LDS read offset (lane-constant across all fragment reads)
  const int q4s = (q4 ^ ((c >> 1) & 3)) * 8;

  const short* Bz0 = Wqb;
  const short* Bz1 = Wkb;
  const short* Bz2 = Wvb;

  // prologue: stage tile 0 -> buf0
#pragma unroll
  for (int st = 0; st < 2; ++st) {
    const int chunk = w * 2 + st;
    const size_t roff = (size_t)(chunk * 16 + arow) * 1024 + acol;
    gl_lds16(A + (size_t)m0 * 1024 + roff, Ab0 + chunk * 512);
    gl_lds16(Bz0 + (size_t)n0 * 1024 + roff, (short*)(smem_raw + 16384) + chunk * 512);
    gl_lds16(Bz1 + (size_t)n0 * 1024 + roff, (short*)(smem_raw + 32768) + chunk * 512);
    gl_lds16(Bz2 + (size_t)n0 * 1024 + roff, (short*)(smem_raw + 49152) + chunk * 512);
  }
  __syncthreads();

  for (int kk = 0; kk < 32; ++kk) {
    const int cur = kk & 1;
    if (kk + 1 < 32) {  // prefetch next K-tile into the other buffer
      const int k0n = (kk + 1) * 32;
#pragma unroll
      for (int st = 0; st < 2; ++st) {
        const int chunk = w * 2 + st;
        const size_t roff = (size_t)(chunk * 16 + arow) * 1024 + k0n + acol;
        gl_lds16(A + (size_t)m0 * 1024 + roff, (cur ? Ab0 : Ab1) + chunk * 512);
        gl_lds16(Bz0 + (size_t)n0 * 1024 + roff,
                 (short*)(smem_raw + 16384 + (cur ? 0 : 8192)) + chunk * 512);
        gl_lds16(Bz1 + (size_t)n0 * 1024 + roff,
                 (short*)(smem_raw + 32768 + (cur ? 0 : 8192)) + chunk * 512);
        gl_lds16(Bz2 + (size_t)n0 * 1024 + roff,
                 (short*)(smem_raw + 49152 + (cur ? 0 : 8192)) + chunk * 512);
      }
    }
    const short* Ab = cur ? Ab1 : Ab0;
    short8 af[4];
#pragma unroll
    for (int i = 0; i < 4; ++i)
      af[i] = *(const short8*)(Ab + (wr * 64 + i * 16 + c) * 32 + q4s);
#pragma unroll
    for (int z = 0; z < 3; ++z) {
      const short* Bb =
          (const short*)(smem_raw + 16384 + z * 16384 + (cur ? 8192 : 0));
      short8 bfr[4];
#pragma unroll
      for (int j = 0; j < 4; ++j)
        bfr[j] = *(const short8*)(Bb + (wc * 64 + j * 16 + c) * 32 + q4s);
#pragma unroll
      for (int i = 0; i < 4; ++i)
#pragma unroll
        for (int j = 0; j < 4; ++j)
          acc[z][i][j] = mfma16(af[i], bfr[j], acc[z][i][j]);
    }
    __syncthreads();  // drains prefetch (overlapped by the 48-MFMA compute)
  }

  // ---- epilogues: Q then K (row-major), then V (transposed), via Cb LDS ----
#pragma unroll
  for (int z = 0; z < 2; ++z) {
    short* Cb = (short*)smem_raw;
    const float* bias = z ? bk : bq;
    short* outp = z ? Ko : Qo;
    const float scale = z ? 1.0f : 0.125f;
#pragma unroll
    for (int j = 0; j < 4; ++j) {
      const float bvv = bias[n0 + wc * 64 + j * 16 + c];
#pragma unroll
      for (int i = 0; i < 4; ++i)
#pragma unroll
        for (int r = 0; r < 4; ++r)
          Cb[(wr * 64 + i * 16 + q4 * 4 + r) * 136 + wc * 64 + j * 16 + c] =
              f2bf((acc[z][i][j][r] + bvv) * scale);
    }
    __syncthreads();
#pragma unroll
    for (int p = 0; p < 8; ++p) {
      const int g = p * 256 + tid;
      const int row = g >> 4, seg = g & 15;
      *(short8*)(outp + (size_t)(m0 + row) * 1024 + n0 + seg * 8) =
          *(const short8*)(Cb + row * 136 + seg * 8);
    }
    __syncthreads();
  }
  {
    short* Cb = (short*)smem_raw;
#pragma unroll
    for (int j = 0; j < 4; ++j) {
      const float bvv = bv[n0 + wc * 64 + j * 16 + c];
#pragma unroll
      for (int i = 0; i < 4; ++i) {
        short4 pk;
        pk.x = f2bf(acc[2][i][j][0] + bvv);
        pk.y = f2bf(acc[2][i][j][1] + bvv);
        pk.z = f2bf(acc[2][i][j][2] + bvv);
        pk.w = f2bf(acc[2][i][j][3] + bvv);
        *(short4*)(Cb + (wc * 64 + j * 16 + c) * 136 + wr * 64 + i * 16 + q4 * 4) = pk;
      }
    }
    __syncthreads();
    const int bb = m0 >> 11;
    const int tokb = m0 & 2047;
#pragma unroll
    for (int p = 0; p < 8; ++p) {
      const int g = p * 256 + tid;
      const int col = g >> 4, rseg = g & 15;
      const int colg = n0 + col;
      const int hh = colg >> 6, dd = colg & 63;
      *(short8*)(Vo + ((size_t)(bb * NH_ + hh) * DH_ + dd) * M_ + tokb + rseg * 8) =
          *(const short8*)(Cb + col * 136 + rseg * 8);
    }
  }
}

// ---------------- output projection GEMM (R13: 128x128 R8-style rewrite) ----------------
// Old structure: 128x64 tile, 8 MFMA/barrier -- the shape R12 just measured
// as ~30% worse (sync:MFMA ratio). New: 128x128 tile, 16 MFMA/barrier,
// 2-phase double-buffered staging, chunk-swizzled LDS (R8-proven pair),
// 512 blocks. fp32 epilogue via LDS [64][132] in two row-halves.
__global__ __launch_bounds__(256, 2) void gemm_oproj(const short* __restrict__ A,
                                                     const short* __restrict__ Bt,
                                                     const float* __restrict__ bias,
                                                     const int* __restrict__ pmask,
                                                     float* __restrict__ outp) {
  __shared__ char smem[33792];           // staging 32K; epilogue 64*132*4 = 33792
  short* Ab0 = (short*)smem;             // 128x32 (8 KB)
  short* Ab1 = (short*)(smem + 8192);
  short* Bb0 = (short*)(smem + 16384);   // 128x32 (8 KB)
  short* Bb1 = (short*)(smem + 24576);

  const int L = blockIdx.x + 8 * blockIdx.y;  // 512 blocks
  const int xcd = L & 7;
  const int s = L >> 3;        // 0..63
  const int m_local = s & 7;
  const int nt = s >> 3;       // 0..7
  const int m0 = (xcd * 8 + m_local) * 128;
  const int n0 = nt * 128;

  const int tid = threadIdx.x;
  const int w = tid >> 6, l = tid & 63;
  const int q4 = l >> 4, c = l & 15;
  const int wr = w >> 1, wc = w & 1;

  f32x4 acc[4][4] = {};
  const int arow = (l >> 2);
  const int acol = ((l & 3) ^ ((l >> 3) & 3)) * 8;   // inverse-swizzled source col
  const int q4s = (q4 ^ ((c >> 1) & 3)) * 8;         // swizzled LDS read offset

  // prologue: tile 0 -> buf0
#pragma unroll
  for (int st = 0; st < 2; ++st) {
    const int chunk = w * 2 + st;
    const size_t roff = (size_t)(chunk * 16 + arow) * 1024 + acol;
    gl_lds16(A + (size_t)m0 * 1024 + roff, Ab0 + chunk * 512);
    gl_lds16(Bt + (size_t)n0 * 1024 + roff, Bb0 + chunk * 512);
  }
  __syncthreads();

  for (int kk = 0; kk < 32; ++kk) {
    const int cur = kk & 1;
    if (kk + 1 < 32) {
      const int k0n = (kk + 1) * 32;
#pragma unroll
      for (int st = 0; st < 2; ++st) {
        const int chunk = w * 2 + st;
        const size_t roff = (size_t)(chunk * 16 + arow) * 1024 + k0n + acol;
        gl_lds16(A + (size_t)m0 * 1024 + roff, (cur ? Ab0 : Ab1) + chunk * 512);
        gl_lds16(Bt + (size_t)n0 * 1024 + roff, (cur ? Bb0 : Bb1) + chunk * 512);
      }
    }
    const short* Ab = cur ? Ab1 : Ab0;
    const short* Bb = cur ? Bb1 : Bb0;
    short8 af[4], bfr[4];
#pragma unroll
    for (int i = 0; i < 4; ++i)
      af[i] = *(const short8*)(Ab + (wr * 64 + i * 16 + c) * 32 + q4s);
#pragma unroll
    for (int j = 0; j < 4; ++j)
      bfr[j] = *(const short8*)(Bb + (wc * 64 + j * 16 + c) * 32 + q4s);
#pragma unroll
    for (int i = 0; i < 4; ++i)
#pragma unroll
      for (int j = 0; j < 4; ++j)
        acc[i][j] = mfma16(af[i], bfr[j], acc[i][j]);
    __syncthreads();
  }

  // fp32 epilogue: two 64-row halves through LDS [64][132], float4 stores
  float* Cf = (float*)smem;
#pragma unroll
  for (int half = 0; half < 2; ++half) {
    __syncthreads();
    if (wr == half) {
#pragma unroll
      for (int j = 0; j < 4; ++j) {
        const float bvv = bias[n0 + wc * 64 + j * 16 + c];
#pragma unroll
        for (int i = 0; i < 4; ++i)
#pragma unroll
          for (int r = 0; r < 4; ++r)
            Cf[(i * 16 + q4 * 4 + r) * 132 + wc * 64 + j * 16 + c] =
                acc[i][j][r] + bvv;
      }
    }
    __syncthreads();
#pragma unroll
    for (int p = 0; p < 8; ++p) {
      const int g = p * 256 + tid;
      const int row = g >> 5, seg = g & 31;
      const int rowg = m0 + half * 64 + row;
      const float mmv = (pmask[rowg] > 0) ? 1.0f : 0.0f;
      float4 v = *(const float4*)(Cf + row * 132 + seg * 4);
      v.x *= mmv; v.y *= mmv; v.z *= mmv; v.w *= mmv;
      *(float4*)(outp + (size_t)rowg * 1024 + n0 + seg * 4) = v;
    }
  }
}

// ---------------- windowed attention (unchanged) ----------------
__global__ __launch_bounds__(256) void attn_kernel(const short* __restrict__ Qb,
                                                   const short* __restrict__ Kb,
                                                   const short* __restrict__ Vtb,
                                                   const int* __restrict__ pmask,
                                                   short* __restrict__ Attb) {
  __shared__ char smem[20480];
  short* Ks0 = (short*)smem;             // 32x64 (4 KB)
  short* Ks1 = (short*)(smem + 4096);
  short* Vs0 = (short*)(smem + 8192);    // 64x32 (4 KB)
  short* Vs1 = (short*)(smem + 12288);
  short* Ps  = (short*)(smem + 16384);   // 4 waves x 16x32 (4 KB)

  const int tid = threadIdx.x;
  const int w = tid >> 6, l = tid & 63;
  const int q4 = l >> 4, c = l & 15;
  const int qt = blockIdx.x, h = blockIdx.y, b = blockIdx.z;
  const short* Qrow = Qb + (size_t)(b * M_) * D_ + h * DH_;
  const short* Kbase = Kb + (size_t)(b * M_) * D_ + h * DH_;
  const short* Vbase = Vtb + (size_t)(b * NH_ + h) * DH_ * M_;
  const int qrow0 = qt * 64 + w * 16;

  short8 aq0 = *(const short8*)(Qrow + (size_t)(qrow0 + c) * D_ + q4 * 8);
  short8 aq1 = *(const short8*)(Qrow + (size_t)(qrow0 + c) * D_ + 32 + q4 * 8);

  const int jt0 = max(0, 2 * qt - 2);
  const int jt1 = min(M_ / 32 - 1, 2 * qt + 3);

  const int kh = tid >> 7, krow = (tid >> 2) & 31, ch = tid & 3;
  const int vrow = tid >> 2;

  {
    const int j0 = jt0 * 32;
    gl_lds16(Kbase + (size_t)(j0 + krow) * D_ + kh * 32 + ch * 8, (char*)Ks0 + tid * 16);
    gl_lds16(Vbase + (size_t)vrow * M_ + j0 + ch * 8, (char*)Vs0 + tid * 16);
  }
  __syncthreads();

  f32x4 o[4] = {};
  float lrun[4] = {0.f, 0.f, 0.f, 0.f};
  short* Pw = Ps + w * 512;

  for (int jt = jt0; jt <= jt1; ++jt) {
    const int buf = (jt - jt0) & 1;
    const int j0 = jt * 32;
    if (jt < jt1) {
      const int j0n = j0 + 32;
      gl_lds16(Kbase + (size_t)(j0n + krow) * D_ + kh * 32 + ch * 8,
               (char*)(buf ? Ks0 : Ks1) + tid * 16);
      gl_lds16(Vbase + (size_t)vrow * M_ + j0n + ch * 8,
               (char*)(buf ? Vs0 : Vs1) + tid * 16);
    }
    const short* Kt = buf ? Ks1 : Ks0;
    const short* Vt = buf ? Vs1 : Vs0;
    short8 b00 = *(const short8*)(Kt + c * 32 + q4 * 8);
    short8 b10 = *(const short8*)(Kt + 1024 + c * 32 + q4 * 8);
    short8 b01 = *(const short8*)(Kt + (16 + c) * 32 + q4 * 8);
    short8 b11 = *(const short8*)(Kt + 1024 + (16 + c) * 32 + q4 * 8);
    f32x4 s0 = {}, s1 = {};
    s0 = mfma16(aq0, b00, s0);
    s0 = mfma16(aq1, b10, s0);
    s1 = mfma16(aq0, b01, s1);
    s1 = mfma16(aq1, b11, s1);

    const float w0m = (pmask[b * M_ + j0 + c] > 0) ? 1.f : 0.f;
    const float w1m = (pmask[b * M_ + j0 + 16 + c] > 0) ? 1.f : 0.f;

#pragma unroll
    for (int r = 0; r < 4; ++r) {
      const int qr = qrow0 + q4 * 4 + r;
      const float d0 = fminf(fabsf((float)(qr - (j0 + c))), 28.0f);
      const float d1 = fminf(fabsf((float)(qr - (j0 + 16 + c))), 28.0f);
      const float p0 = exp2f((s0[r] - d0) * LOG2E) * w0m;
      const float p1 = exp2f((s1[r] - d1) * LOG2E) * w1m;
      Pw[(q4 * 4 + r) * 32 + c] = f2bf(p0);
      Pw[(q4 * 4 + r) * 32 + 16 + c] = f2bf(p1);
      lrun[r] += p0 + p1;
    }
    short8 pa = *(const short8*)(Pw + c * 32 + q4 * 8);
#pragma unroll
    for (int f = 0; f < 4; ++f) {
      short8 bv = *(const short8*)(Vt + (f * 16 + c) * 32 + q4 * 8);
      o[f] = mfma16(pa, bv, o[f]);
    }
    __syncthreads();
  }

#pragma unroll
  for (int r = 0; r < 4; ++r) {
#pragma unroll
    for (int off = 1; off < 16; off <<= 1)
      lrun[r] += __shfl_xor(lrun[r], off);
  }

  short* Cb = (short*)smem;
#pragma unroll
  for (int r = 0; r < 4; ++r) {
    const float inv = 1.0f / lrun[r];
#pragma unroll
    for (int f = 0; f < 4; ++f)
      Cb[(w * 16 + q4 * 4 + r) * 72 + f * 16 + c] = f2bf(o[f][r] * inv);
  }
  __syncthreads();
#pragma unroll
  for (int p = 0; p < 2; ++p) {
    const int u = p * 256 + tid;
    const int row = u >> 3, seg = u & 7;
    *(short8*)(Attb + (size_t)(b * M_ + qt * 64 + row) * D_ + h * DH_ + seg * 8) =
        *(const short8*)(Cb + row * 72 + seg * 8);
  }
}

extern "C" void kernel_launch(void* const* d_in, const int* in_sizes, int n_in,
                              void* d_out, int out_size, void* d_ws, size_t ws_size,
                              hipStream_t stream) {
  const float* H     = (const float*)d_in[0];
  const int*   pmask = (const int*)d_in[1];
  const float* Wq    = (const float*)d_in[2];
  const float* bq    = (const float*)d_in[3];
  const float* Wk    = (const float*)d_in[4];
  const float* bk    = (const float*)d_in[5];
  const float* Wv    = (const float*)d_in[6];
  const float* bv    = (const float*)d_in[7];
  const float* Wo    = (const float*)d_in[8];
  const float* bo    = (const float*)d_in[9];
  float* out = (float*)d_out;
  char* ws = (char*)d_ws;

  short* Hb   = (short*)(ws);                  // 16 MB  (B*M x D bf16)
  short* Attb = (short*)(ws);                  // alias of Hb (dead after qkv)
  short* Wqb  = (short*)(ws + (16u << 20));
  short* Wkb  = (short*)(ws + (18u << 20));
  short* Wvb  = (short*)(ws + (20u << 20));
  short* Wob  = (short*)(ws + (22u << 20));
  short* Qb   = (short*)(ws + (24u << 20));    // 16 MB (B*M,1024), pre-scaled 1/8
  short* Kb2  = (short*)(ws + (40u << 20));    // 16 MB (B*M,1024)
  short* Vtb  = (short*)(ws + (56u << 20));    // 16 MB (B,NH,DH,M)

  cvt_all<<<8192 + 4096, 256, 0, stream>>>(H, Wq, Wk, Wv, Wo,
                                           Hb, Wqb, Wkb, Wvb, Wob);

  gemm_qkv<<<dim3(8, 64), 256, 0, stream>>>(Hb, Wqb, Wkb, Wvb, bq, bk, bv,
                                            Qb, Kb2, Vtb);

  attn_kernel<<<dim3(M_ / 64, NH_, B_), 256, 0, stream>>>(Qb, Kb2, Vtb, pmask, Attb);

  gemm_oproj<<<dim3(8, 64), 256, 0, stream>>>(Attb, Wob, bo, pmask, out);
}

// Round 7
// 207.360 us; speedup vs baseline: 1.7698x; 1.0107x over previous
//
#include <hip/hip_runtime.h>
#include <stdint.h>

typedef short short8 __attribute__((ext_vector_type(8)));
typedef float f32x4 __attribute__((ext_vector_type(4)));

#define B_    4
#define M_    2048
#define D_    1024
#define NH_   16
#define DH_   64
#define LOG2E 1.44269504f

#if __has_builtin(__builtin_amdgcn_exp2f)
#define EXP2F(x) __builtin_amdgcn_exp2f(x)
#else
#define EXP2F(x) exp2f(x)
#endif

__device__ __forceinline__ short f2bf(float f) {
  union { float f; uint32_t u; } v; v.f = f;
  uint32_t r = (v.u + 0x7fffu + ((v.u >> 16) & 1u)) >> 16;  // RNE
  return (short)r;
}

__device__ __forceinline__ void gl_lds16(const void* g, void* l) {
  __builtin_amdgcn_global_load_lds(
      (__attribute__((address_space(1))) void*)(g),
      (__attribute__((address_space(3))) void*)(l),
      16, 0, 0);
}

__device__ __forceinline__ f32x4 mfma16(short8 a, short8 b, f32x4 c) {
  return __builtin_amdgcn_mfma_f32_16x16x32_bf16(a, b, c, 0, 0, 0);
}

// counted waits (separate from barriers; barriers stay compiler-visible)
#define VM_WAIT(N)  asm volatile("s_waitcnt vmcnt(" #N ")" ::: "memory")

// ---------------- fp32 -> bf16 cast, all 5 tensors in one launch ----------------
__global__ __launch_bounds__(256) void cvt_all(const float* __restrict__ H,
                                               const float* __restrict__ s0,
                                               const float* __restrict__ s1,
                                               const float* __restrict__ s2,
                                               const float* __restrict__ s3,
                                               short* __restrict__ dH,
                                               short* __restrict__ d0,
                                               short* __restrict__ d1,
                                               short* __restrict__ d2,
                                               short* __restrict__ d3) {
  const int bidx = blockIdx.x;
  const float* src;
  short* dst;
  int i;
  if (bidx < 8192) {
    src = H; dst = dH; i = bidx * 256 + threadIdx.x;
  } else {
    const int y = (bidx - 8192) >> 10;
    src = (y == 0) ? s0 : (y == 1) ? s1 : (y == 2) ? s2 : s3;
    dst = (y == 0) ? d0 : (y == 1) ? d1 : (y == 2) ? d2 : d3;
    i = ((bidx - 8192) & 1023) * 256 + threadIdx.x;
  }
  float4 v = ((const float4*)src)[i];
  short4 o;
  o.x = f2bf(v.x); o.y = f2bf(v.y); o.z = f2bf(v.z); o.w = f2bf(v.w);
  ((short4*)dst)[i] = o;
}

// ---------------- fused QKV projection GEMM (R8 structure -- measured best) ----------------
// 55us = 937 TF effective = m97-structure plain-HIP ceiling (MfmaUtil ~38%).
// R14 change: Q epilogue scale folds LOG2E (0.125*1.4427) so attn runs its
// softmax entirely in exp2 domain (saves per-element VALU there).
__global__ __launch_bounds__(256, 2) void gemm_qkv(const short* __restrict__ A,
                                                   const short* __restrict__ Wqb,
                                                   const short* __restrict__ Wkb,
                                                   const short* __restrict__ Wvb,
                                                   const float* __restrict__ bq,
                                                   const float* __restrict__ bk,
                                                   const float* __restrict__ bv,
                                                   short* __restrict__ Qo,
                                                   short* __restrict__ Ko,
                                                   short* __restrict__ Vo) {
  __shared__ char smem_raw[65536];
  short* Ab0 = (short*)smem_raw;            // 128x32 (8 KB)
  short* Ab1 = (short*)(smem_raw + 8192);
  // B buffers: z in {0,1,2}, buf in {0,1}: smem + 16384 + z*16384 + buf*8192

  const int L = blockIdx.x + 8 * blockIdx.y;  // 512 blocks
  const int xcd = L & 7;
  const int s = L >> 3;        // 0..63
  const int m_local = s & 7;
  const int nt = s >> 3;       // 0..7
  const int m0 = (xcd * 8 + m_local) * 128;
  const int n0 = nt * 128;

  const int tid = threadIdx.x;
  const int w = tid >> 6, l = tid & 63;
  const int q4 = l >> 4, c = l & 15;
  const int wr = w >> 1, wc = w & 1;

  f32x4 acc[3][4][4] = {};
  const int arow = (l >> 2);
  // inverse-swizzled global source column (16B chunk permutation within 64B row)
  const int acol = ((l & 3) ^ ((l >> 3) & 3)) * 8;
  // swizzled LDS read offset (lane-constant across all fragment reads)
  const int q4s = (q4 ^ ((c >> 1) & 3)) * 8;

  const short* Bz0 = Wqb;
  const short* Bz1 = Wkb;
  const short* Bz2 = Wvb;

  // prologue: stage tile 0 -> buf0
#pragma unroll
  for (int st = 0; st < 2; ++st) {
    const int chunk = w * 2 + st;
    const size_t roff = (size_t)(chunk * 16 + arow) * 1024 + acol;
    gl_lds16(A + (size_t)m0 * 1024 + roff, Ab0 + chunk * 512);
    gl_lds16(Bz0 + (size_t)n0 * 1024 + roff, (short*)(smem_raw + 16384) + chunk * 512);
    gl_lds16(Bz1 + (size_t)n0 * 1024 + roff, (short*)(smem_raw + 32768) + chunk * 512);
    gl_lds16(Bz2 + (size_t)n0 * 1024 + roff, (short*)(smem_raw + 49152) + chunk * 512);
  }
  __syncthreads();

  for (int kk = 0; kk < 32; ++kk) {
    const int cur = kk & 1;
    if (kk + 1 < 32) {  // prefetch next K-tile into the other buffer
      const int k0n = (kk + 1) * 32;
#pragma unroll
      for (int st = 0; st < 2; ++st) {
        const int chunk = w * 2 + st;
        const size_t roff = (size_t)(chunk * 16 + arow) * 1024 + k0n + acol;
        gl_lds16(A + (size_t)m0 * 1024 + roff, (cur ? Ab0 : Ab1) + chunk * 512);
        gl_lds16(Bz0 + (size_t)n0 * 1024 + roff,
                 (short*)(smem_raw + 16384 + (cur ? 0 : 8192)) + chunk * 512);
        gl_lds16(Bz1 + (size_t)n0 * 1024 + roff,
                 (short*)(smem_raw + 32768 + (cur ? 0 : 8192)) + chunk * 512);
        gl_lds16(Bz2 + (size_t)n0 * 1024 + roff,
                 (short*)(smem_raw + 49152 + (cur ? 0 : 8192)) + chunk * 512);
      }
    }
    const short* Ab = cur ? Ab1 : Ab0;
    short8 af[4];
#pragma unroll
    for (int i = 0; i < 4; ++i)
      af[i] = *(const short8*)(Ab + (wr * 64 + i * 16 + c) * 32 + q4s);
#pragma unroll
    for (int z = 0; z < 3; ++z) {
      const short* Bb =
          (const short*)(smem_raw + 16384 + z * 16384 + (cur ? 8192 : 0));
      short8 bfr[4];
#pragma unroll
      for (int j = 0; j < 4; ++j)
        bfr[j] = *(const short8*)(Bb + (wc * 64 + j * 16 + c) * 32 + q4s);
#pragma unroll
      for (int i = 0; i < 4; ++i)
#pragma unroll
        for (int j = 0; j < 4; ++j)
          acc[z][i][j] = mfma16(af[i], bfr[j], acc[z][i][j]);
    }
    __syncthreads();  // drains prefetch (overlapped by the 48-MFMA compute)
  }

  // ---- epilogues: Q then K (row-major), then V (transposed), via Cb LDS ----
#pragma unroll
  for (int z = 0; z < 2; ++z) {
    short* Cb = (short*)smem_raw;
    const float* bias = z ? bk : bq;
    short* outp = z ? Ko : Qo;
    // Q is pre-scaled by 1/sqrt(dh) AND log2(e): attn softmax runs in exp2 domain
    const float scale = z ? 1.0f : (0.125f * LOG2E);
#pragma unroll
    for (int j = 0; j < 4; ++j) {
      const float bvv = bias[n0 + wc * 64 + j * 16 + c];
#pragma unroll
      for (int i = 0; i < 4; ++i)
#pragma unroll
        for (int r = 0; r < 4; ++r)
          Cb[(wr * 64 + i * 16 + q4 * 4 + r) * 136 + wc * 64 + j * 16 + c] =
              f2bf((acc[z][i][j][r] + bvv) * scale);
    }
    __syncthreads();
#pragma unroll
    for (int p = 0; p < 8; ++p) {
      const int g = p * 256 + tid;
      const int row = g >> 4, seg = g & 15;
      *(short8*)(outp + (size_t)(m0 + row) * 1024 + n0 + seg * 8) =
          *(const short8*)(Cb + row * 136 + seg * 8);
    }
    __syncthreads();
  }
  {
    short* Cb = (short*)smem_raw;
#pragma unroll
    for (int j = 0; j < 4; ++j) {
      const float bvv = bv[n0 + wc * 64 + j * 16 + c];
#pragma unroll
      for (int i = 0; i < 4; ++i) {
        short4 pk;
        pk.x = f2bf(acc[2][i][j][0] + bvv);
        pk.y = f2bf(acc[2][i][j][1] + bvv);
        pk.z = f2bf(acc[2][i][j][2] + bvv);
        pk.w = f2bf(acc[2][i][j][3] + bvv);
        *(short4*)(Cb + (wc * 64 + j * 16 + c) * 136 + wr * 64 + i * 16 + q4 * 4) = pk;
      }
    }
    __syncthreads();
    const int bb = m0 >> 11;
    const int tokb = m0 & 2047;
#pragma unroll
    for (int p = 0; p < 8; ++p) {
      const int g = p * 256 + tid;
      const int col = g >> 4, rseg = g & 15;
      const int colg = n0 + col;
      const int hh = colg >> 6, dd = colg & 63;
      *(short8*)(Vo + ((size_t)(bb * NH_ + hh) * DH_ + dd) * M_ + tokb + rseg * 8) =
          *(const short8*)(Cb + col * 136 + rseg * 8);
    }
  }
}

// ---------------- output projection GEMM (R13 128x128 structure, unchanged) ----------------
__global__ __launch_bounds__(256, 2) void gemm_oproj(const short* __restrict__ A,
                                                     const short* __restrict__ Bt,
                                                     const float* __restrict__ bias,
                                                     const int* __restrict__ pmask,
                                                     float* __restrict__ outp) {
  __shared__ char smem[33792];           // staging 32K; epilogue 64*132*4 = 33792
  short* Ab0 = (short*)smem;             // 128x32 (8 KB)
  short* Ab1 = (short*)(smem + 8192);
  short* Bb0 = (short*)(smem + 16384);   // 128x32 (8 KB)
  short* Bb1 = (short*)(smem + 24576);

  const int L = blockIdx.x + 8 * blockIdx.y;  // 512 blocks
  const int xcd = L & 7;
  const int s = L >> 3;        // 0..63
  const int m_local = s & 7;
  const int nt = s >> 3;       // 0..7
  const int m0 = (xcd * 8 + m_local) * 128;
  const int n0 = nt * 128;

  const int tid = threadIdx.x;
  const int w = tid >> 6, l = tid & 63;
  const int q4 = l >> 4, c = l & 15;
  const int wr = w >> 1, wc = w & 1;

  f32x4 acc[4][4] = {};
  const int arow = (l >> 2);
  const int acol = ((l & 3) ^ ((l >> 3) & 3)) * 8;   // inverse-swizzled source col
  const int q4s = (q4 ^ ((c >> 1) & 3)) * 8;         // swizzled LDS read offset

  // prologue: tile 0 -> buf0
#pragma unroll
  for (int st = 0; st < 2; ++st) {
    const int chunk = w * 2 + st;
    const size_t roff = (size_t)(chunk * 16 + arow) * 1024 + acol;
    gl_lds16(A + (size_t)m0 * 1024 + roff, Ab0 + chunk * 512);
    gl_lds16(Bt + (size_t)n0 * 1024 + roff, Bb0 + chunk * 512);
  }
  __syncthreads();

  for (int kk = 0; kk < 32; ++kk) {
    const int cur = kk & 1;
    if (kk + 1 < 32) {
      const int k0n = (kk + 1) * 32;
#pragma unroll
      for (int st = 0; st < 2; ++st) {
        const int chunk = w * 2 + st;
        const size_t roff = (size_t)(chunk * 16 + arow) * 1024 + k0n + acol;
        gl_lds16(A + (size_t)m0 * 1024 + roff, (cur ? Ab0 : Ab1) + chunk * 512);
        gl_lds16(Bt + (size_t)n0 * 1024 + roff, (cur ? Bb0 : Bb1) + chunk * 512);
      }
    }
    const short* Ab = cur ? Ab1 : Ab0;
    const short* Bb = cur ? Bb1 : Bb0;
    short8 af[4], bfr[4];
#pragma unroll
    for (int i = 0; i < 4; ++i)
      af[i] = *(const short8*)(Ab + (wr * 64 + i * 16 + c) * 32 + q4s);
#pragma unroll
    for (int j = 0; j < 4; ++j)
      bfr[j] = *(const short8*)(Bb + (wc * 64 + j * 16 + c) * 32 + q4s);
#pragma unroll
    for (int i = 0; i < 4; ++i)
#pragma unroll
      for (int j = 0; j < 4; ++j)
        acc[i][j] = mfma16(af[i], bfr[j], acc[i][j]);
    __syncthreads();
  }

  // fp32 epilogue: two 64-row halves through LDS [64][132], float4 stores
  float* Cf = (float*)smem;
#pragma unroll
  for (int half = 0; half < 2; ++half) {
    __syncthreads();
    if (wr == half) {
#pragma unroll
      for (int j = 0; j < 4; ++j) {
        const float bvv = bias[n0 + wc * 64 + j * 16 + c];
#pragma unroll
        for (int i = 0; i < 4; ++i)
#pragma unroll
          for (int r = 0; r < 4; ++r)
            Cf[(i * 16 + q4 * 4 + r) * 132 + wc * 64 + j * 16 + c] =
                acc[i][j][r] + bvv;
      }
    }
    __syncthreads();
#pragma unroll
    for (int p = 0; p < 8; ++p) {
      const int g = p * 256 + tid;
      const int row = g >> 5, seg = g & 31;
      const int rowg = m0 + half * 64 + row;
      const float mmv = (pmask[rowg] > 0) ? 1.0f : 0.0f;
      float4 v = *(const float4*)(Cf + row * 132 + seg * 4);
      v.x *= mmv; v.y *= mmv; v.z *= mmv; v.w *= mmv;
      *(float4*)(outp + (size_t)rowg * 1024 + n0 + seg * 4) = v;
    }
  }
}

// ---------------- windowed attention (R14: VALU trim + counted-vmcnt) ----------------
// Theory: jt-loop is VALU-bound (~110 VALU + 8 guarded-exp2 vs 8 MFMA/lane/tile),
// and __syncthreads' implicit vmcnt(0) drained the same-iteration K/V prefetch.
// Fixes: (1) softmax in exp2 domain (Q pre-scaled by log2e in gemm_qkv; bias
// constants pre-multiplied) -- d-chain is now 1 add + 1 abs-folded min;
// (2) raw v_exp_f32 via builtin (args bounded, guards unneeded);
// (3) counted vmcnt(2) + raw barriers, loads get a full iteration to land;
// (4) setprio around MFMA clusters (T5, +4-7% measured on attn-class kernels).
__global__ __launch_bounds__(256) void attn_kernel(const short* __restrict__ Qb,
                                                   const short* __restrict__ Kb,
                                                   const short* __restrict__ Vtb,
                                                   const int* __restrict__ pmask,
                                                   short* __restrict__ Attb) {
  __shared__ char smem[20480];
  short* Ks0 = (short*)smem;             // 32x64 (4 KB)
  short* Ks1 = (short*)(smem + 4096);
  short* Vs0 = (short*)(smem + 8192);    // 64x32 (4 KB)
  short* Vs1 = (short*)(smem + 12288);
  short* Ps  = (short*)(smem + 16384);   // 4 waves x 16x32 (4 KB)

  const int tid = threadIdx.x;
  const int w = tid >> 6, l = tid & 63;
  const int q4 = l >> 4, c = l & 15;
  const int qt = blockIdx.x, h = blockIdx.y, b = blockIdx.z;
  const short* Qrow = Qb + (size_t)(b * M_) * D_ + h * DH_;
  const short* Kbase = Kb + (size_t)(b * M_) * D_ + h * DH_;
  const short* Vbase = Vtb + (size_t)(b * NH_ + h) * DH_ * M_;
  const int* pm = pmask + b * M_;
  const int qrow0 = qt * 64 + w * 16;

  short8 aq0 = *(const short8*)(Qrow + (size_t)(qrow0 + c) * D_ + q4 * 8);
  short8 aq1 = *(const short8*)(Qrow + (size_t)(qrow0 + c) * D_ + 32 + q4 * 8);

  const int jt0 = max(0, 2 * qt - 2);
  const int jt1 = min(M_ / 32 - 1, 2 * qt + 3);

  const int kh = tid >> 7, krow = (tid >> 2) & 31, ch = tid & 3;
  const int vrow = tid >> 2;

  // prologue: issue jt0's K/V loads (2 gl_lds/thread); first in-loop wait covers them
  {
    const int j0 = jt0 * 32;
    gl_lds16(Kbase + (size_t)(j0 + krow) * D_ + kh * 32 + ch * 8, (char*)Ks0 + tid * 16);
    gl_lds16(Vbase + (size_t)vrow * M_ + j0 + ch * 8, (char*)Vs0 + tid * 16);
  }

  f32x4 o[4] = {};
  float lrun[4] = {0.f, 0.f, 0.f, 0.f};
  short* Pw = Ps + w * 512;
  const int ib = qrow0 + q4 * 4 - c;   // lane-invariant query/key index delta base
  const float CLAMP = 28.0f * LOG2E;   // 40.395461
  const float C16   = 16.0f * LOG2E;   // 23.083121

  for (int jt = jt0; jt <= jt1; ++jt) {
    const int buf = (jt - jt0) & 1;
    const int j0 = jt * 32;
    if (jt < jt1) {
      const int j0n = j0 + 32;
      gl_lds16(Kbase + (size_t)(j0n + krow) * D_ + kh * 32 + ch * 8,
               (char*)(buf ? Ks0 : Ks1) + tid * 16);
      gl_lds16(Vbase + (size_t)vrow * M_ + j0n + ch * 8,
               (char*)(buf ? Vs0 : Vs1) + tid * 16);
      VM_WAIT(2);          // this tile's 2 loads landed; next tile's 2 in flight
    } else {
      VM_WAIT(0);          // last tile: drain
    }
    __builtin_amdgcn_sched_barrier(0);
    __builtin_amdgcn_s_barrier();      // all waves' waits passed -> tile resident
    __builtin_amdgcn_sched_barrier(0);

    const short* Kt = buf ? Ks1 : Ks0;
    const short* Vt = buf ? Vs1 : Vs0;
    short8 b00 = *(const short8*)(Kt + c * 32 + q4 * 8);
    short8 b10 = *(const short8*)(Kt + 1024 + c * 32 + q4 * 8);
    short8 b01 = *(const short8*)(Kt + (16 + c) * 32 + q4 * 8);
    short8 b11 = *(const short8*)(Kt + 1024 + (16 + c) * 32 + q4 * 8);
    f32x4 s0 = {}, s1 = {};
    __builtin_amdgcn_s_setprio(1);
    s0 = mfma16(aq0, b00, s0);
    s0 = mfma16(aq1, b10, s0);
    s1 = mfma16(aq0, b01, s1);
    s1 = mfma16(aq1, b11, s1);
    __builtin_amdgcn_s_setprio(0);

    const float w0m = (pm[j0 + c] > 0) ? 1.f : 0.f;
    const float w1m = (pm[j0 + 16 + c] > 0) ? 1.f : 0.f;
    // e-base in exp2 domain: (ib - j0)*log2e; per-r offsets are literals
    const float eb = (float)(ib - j0) * LOG2E;

#pragma unroll
    for (int r = 0; r < 4; ++r) {
      const float er = eb + (float)r * LOG2E;          // literal per unrolled r
      const float d0 = fminf(fabsf(er), CLAMP);        // abs folds into min
      const float d1 = fminf(fabsf(er - C16), CLAMP);
      const float p0 = EXP2F(s0[r] - d0) * w0m;        // s already in exp2 domain
      const float p1 = EXP2F(s1[r] - d1) * w1m;
      Pw[(q4 * 4 + r) * 32 + c] = f2bf(p0);
      Pw[(q4 * 4 + r) * 32 + 16 + c] = f2bf(p1);
      lrun[r] += p0 + p1;
    }
    short8 pa = *(const short8*)(Pw + c * 32 + q4 * 8);
    __builtin_amdgcn_s_setprio(1);
#pragma unroll
    for (int f = 0; f < 4; ++f) {
      short8 bv = *(const short8*)(Vt + (f * 16 + c) * 32 + q4 * 8);
      o[f] = mfma16(pa, bv, o[f]);
    }
    __builtin_amdgcn_s_setprio(0);
    __builtin_amdgcn_sched_barrier(0);
    __builtin_amdgcn_s_barrier();      // all waves done reading this buffer
  }

#pragma unroll
  for (int r = 0; r < 4; ++r) {
#pragma unroll
    for (int off = 1; off < 16; off <<= 1)
      lrun[r] += __shfl_xor(lrun[r], off);
  }

  short* Cb = (short*)smem;
#pragma unroll
  for (int r = 0; r < 4; ++r) {
    const float inv = 1.0f / lrun[r];
#pragma unroll
    for (int f = 0; f < 4; ++f)
      Cb[(w * 16 + q4 * 4 + r) * 72 + f * 16 + c] = f2bf(o[f][r] * inv);
  }
  __syncthreads();
#pragma unroll
  for (int p = 0; p < 2; ++p) {
    const int u = p * 256 + tid;
    const int row = u >> 3, seg = u & 7;
    *(short8*)(Attb + (size_t)(b * M_ + qt * 64 + row) * D_ + h * DH_ + seg * 8) =
        *(const short8*)(Cb + row * 72 + seg * 8);
  }
}

extern "C" void kernel_launch(void* const* d_in, const int* in_sizes, int n_in,
                              void* d_out, int out_size, void* d_ws, size_t ws_size,
                              hipStream_t stream) {
  const float* H     = (const float*)d_in[0];
  const int*   pmask = (const int*)d_in[1];
  const float* Wq    = (const float*)d_in[2];
  const float* bq    = (const float*)d_in[3];
  const float* Wk    = (const float*)d_in[4];
  const float* bk    = (const float*)d_in[5];
  const float* Wv    = (const float*)d_in[6];
  const float* bv    = (const float*)d_in[7];
  const float* Wo    = (const float*)d_in[8];
  const float* bo    = (const float*)d_in[9];
  float* out = (float*)d_out;
  char* ws = (char*)d_ws;

  short* Hb   = (short*)(ws);                  // 16 MB  (B*M x D bf16)
  short* Attb = (short*)(ws);                  // alias of Hb (dead after qkv)
  short* Wqb  = (short*)(ws + (16u << 20));
  short* Wkb  = (short*)(ws + (18u << 20));
  short* Wvb  = (short*)(ws + (20u << 20));
  short* Wob  = (short*)(ws + (22u << 20));
  short* Qb   = (short*)(ws + (24u << 20));    // 16 MB (B*M,1024), pre-scaled 0.125*log2e
  short* Kb2  = (short*)(ws + (40u << 20));    // 16 MB (B*M,1024)
  short* Vtb  = (short*)(ws + (56u << 20));    // 16 MB (B,NH,DH,M)

  cvt_all<<<8192 + 4096, 256, 0, stream>>>(H, Wq, Wk, Wv, Wo,
                                           Hb, Wqb, Wkb, Wvb, Wob);

  gemm_qkv<<<dim3(8, 64), 256, 0, stream>>>(Hb, Wqb, Wkb, Wvb, bq, bk, bv,
                                            Qb, Kb2, Vtb);

  attn_kernel<<<dim3(M_ / 64, NH_, B_), 256, 0, stream>>>(Qb, Kb2, Vtb, pmask, Attb);

  gemm_oproj<<<dim3(8, 64), 256, 0, stream>>>(Attb, Wob, bo, pmask, out);
}